// Round 17
// baseline (202.007 us; speedup 1.0000x reference)
//
#include <hip/hip_runtime.h>

#define HWp 9216
#define CD 128
#define RC 64
#define NB 2
#define KSPLIT 4
#define NSTEPS 72           // key-blocks of 32 per wave
#define LOG2E 1.4426950408889634f

// fragment-layout strides (in shorts)
#define E2F_NSTR 589824     // (HWp/32) kb * 4 frags * 64 lanes * 8
#define AVF_NSTR 1179648    // (HWp/32) kb * 8 frags * 64 lanes * 8

typedef short s16x8 __attribute__((ext_vector_type(8)));
typedef unsigned short u16x8 __attribute__((ext_vector_type(8)));
typedef float fx4 __attribute__((ext_vector_type(4)));

__device__ __forceinline__ unsigned short f2bf(float f) {
    union { float f; unsigned int u; } cv; cv.f = f;
    unsigned int u = cv.u;
    u += 0x7FFFu + ((u >> 16) & 1u);
    return (unsigned short)(u >> 16);
}

__device__ __forceinline__ float fexp2(float x) {
    float r; asm("v_exp_f32 %0, %1" : "=v"(r) : "v"(x)); return r;
}

__device__ __forceinline__ unsigned int cvt_pk_bf16(float lo, float hi) {
    unsigned int r; asm("v_cvt_pk_bf16_f32 %0, %1, %2" : "=v"(r) : "v"(lo), "v"(hi)); return r;
}

__device__ __forceinline__ const float* uniform_ptr(const float* p) {
    unsigned long long v = (unsigned long long)(uintptr_t)p;
    unsigned int lo = __builtin_amdgcn_readfirstlane((unsigned int)v);
    unsigned int hi = __builtin_amdgcn_readfirstlane((unsigned int)(v >> 32));
    return (const float*)(uintptr_t)(((unsigned long long)hi << 32) | lo);
}

// Projections. R12-VERBATIM (passed R12/R14/R16, ~72-75us). Grid (144, NB, 8); 256 thr.
__global__ __launch_bounds__(256) void proj_kernel(
    const float* __restrict__ x,
    const float* __restrict__ w1, const float* __restrict__ b1, const float* __restrict__ a1,
    const float* __restrict__ w2, const float* __restrict__ b2, const float* __restrict__ a2,
    const float* __restrict__ wa, const float* __restrict__ ba, const float* __restrict__ aa,
    unsigned short* __restrict__ e1, unsigned short* __restrict__ e2f,
    unsigned short* __restrict__ avf)
{
    const int n = blockIdx.y;
    const int p0 = blockIdx.x * 64;
    const int wv = threadIdx.x >> 6;
    const int lane = threadIdx.x & 63;
    const int p = p0 + lane;
    const int row0 = blockIdx.z * 32 + wv * 8;   // 0..255 in [e1(64) | e2(64) | av(128)]
    const float* __restrict__ xb = x + (size_t)n * CD * HWp;

    const float* W; const float* B; const float* A; int r0; int mode; float oscale = 1.0f;
    if (row0 < 64)       { W = w1; B = b1; A = a1; r0 = row0;       mode = 0; oscale = LOG2E; }
    else if (row0 < 128) { W = w2; B = b2; A = a2; r0 = row0 - 64;  mode = 1; }
    else                 { W = wa; B = ba; A = aa; r0 = row0 - 128; mode = 2; }
    W = uniform_ptr(W); B = uniform_ptr(B);
    const float slope = A[0];

    float acc[8];
#pragma unroll
    for (int j = 0; j < 8; ++j) acc[j] = B[r0 + j];
    for (int cc = 0; cc < 4; ++cc) {
        float xr[32];
#pragma unroll
        for (int i = 0; i < 32; ++i) xr[i] = xb[(size_t)(cc * 32 + i) * HWp + p];
#pragma unroll
        for (int j = 0; j < 8; ++j) {
            const float* Wr = W + (size_t)(r0 + j) * CD + cc * 32;
            float a = acc[j];
#pragma unroll
            for (int i = 0; i < 32; ++i) a = __builtin_fmaf(Wr[i], xr[i], a);
            acc[j] = a;
        }
    }
#pragma unroll
    for (int j = 0; j < 8; ++j) {
        float v = acc[j];
        acc[j] = (v >= 0.f ? v : slope * v) * oscale;
    }
    if (mode == 0) {
        u16x8 s0;
#pragma unroll
        for (int j = 0; j < 8; ++j) s0[j] = f2bf(acc[j]);
        unsigned short* dst = e1 + ((size_t)n * HWp + p) * RC + r0;
        *(u16x8*)(dst) = s0;
    } else if (mode == 1) {
        u16x8 s0;
#pragma unroll
        for (int j = 0; j < 8; ++j) s0[j] = f2bf(acc[j]);
        const int kb = p >> 5, kk = p & 31;
        const int l15w = ((kk >> 3) << 2) | (kk & 3);
        const int hw = (kk >> 2) & 1;
        const int ch = r0 >> 5;
        const int gA = (r0 >> 3) & 3;
        unsigned short* dst = e2f + (size_t)n * E2F_NSTR
                            + ((size_t)((kb * 4 + hw * 2 + ch) * 64 + gA * 16 + l15w)) * 8;
        *(u16x8*)(dst) = s0;
    } else {
        const int kb = p >> 5, gw = (p >> 3) & 3, jj = p & 7;
        const int ct = r0 >> 4;
        const int lbase = r0 & 15;
        unsigned short* base = avf + (size_t)n * AVF_NSTR
                             + ((size_t)((kb * 8 + ct) * 64 + gw * 16)) * 8 + jj;
#pragma unroll
        for (int j = 0; j < 8; ++j)
            base[(lbase + j) * 8] = f2bf(acc[j]);
    }
}

// Flash attention. R16 base (passed, 107.4us) + af one-step-ahead double-buffer
// (same prefetch-rotation pattern class as kf, proven in R9/R10).
__global__ __launch_bounds__(256, 1) void attn_kernel(
    const unsigned short* __restrict__ e1,
    const unsigned short* __restrict__ e2f,
    const unsigned short* __restrict__ avf,
    float* __restrict__ out)
{
    const int wv = threadIdx.x >> 6;
    const int lane = threadIdx.x & 63;
    const int g = lane >> 4;
    const int l15 = lane & 15;

    // XCD swizzle (R2-verbatim): batch 0 -> XCDs 0-3, batch 1 -> XCDs 4-7
    const int bid = blockIdx.x;
    const int xcd = bid & 7;
    const int n = xcd >> 2;
    const int qslot = (xcd & 3) * 72 + (bid >> 3);   // [0,288)
    const int qb = qslot * 32;

    const unsigned short* __restrict__ E1 = e1 + (size_t)n * HWp * RC;
    const unsigned short* __restrict__ E2F = e2f + (size_t)n * E2F_NSTR;
    const unsigned short* __restrict__ AVF = avf + (size_t)n * AVF_NSTR;

    // Q fragments (B operand): col = query = l15, k = channel = ch*32 + g*8 + j
    s16x8 qf[2][2];
#pragma unroll
    for (int qc = 0; qc < 2; ++qc)
#pragma unroll
        for (int ch = 0; ch < 2; ++ch)
            qf[qc][ch] = *(const s16x8*)(E1 + ((size_t)(qb + qc * 16 + l15)) * RC + ch * 32 + g * 8);

    s16x8 ones;
#pragma unroll
    for (int j = 0; j < 8; ++j) ones[j] = (short)0x3F80;   // bf16 1.0

    fx4 oacc[2][8];
    fx4 lacc[2];
#pragma unroll
    for (int qc = 0; qc < 2; ++qc) {
        lacc[qc] = (fx4){0.f, 0.f, 0.f, 0.f};
#pragma unroll
        for (int ct = 0; ct < 8; ++ct) oacc[qc][ct] = (fx4){0.f, 0.f, 0.f, 0.f};
    }

    const int kb0 = wv * NSTEPS;   // first key-block of this wave

    // running pointers (shorts): kf frag f at kfp + f*512; af frag ct at afp + ct*512
    const unsigned short* kfp = E2F + (size_t)kb0 * 2048 + (size_t)lane * 8;
    const unsigned short* afp = AVF + (size_t)kb0 * 4096 + (size_t)lane * 8;

    // prologue: prefetch kf AND af for kb0
    s16x8 kfc[2][2];
#pragma unroll
    for (int h = 0; h < 2; ++h)
#pragma unroll
        for (int ch = 0; ch < 2; ++ch)
            kfc[h][ch] = *(const s16x8*)(kfp + (h * 2 + ch) * 512);
    kfp += 2048;

    s16x8 afc[8];
#pragma unroll
    for (int ct = 0; ct < 8; ++ct)
        afc[ct] = *(const s16x8*)(afp + ct * 512);
    afp += 4096;

    union { s16x8 v; unsigned int w[4]; } pf[2];

    for (int kt = 0; kt < NSTEPS; ++kt) {
        const bool more = (kt + 1 < NSTEPS);

        // 1) issue af prefetch for NEXT step (full step of latency cover)
        const unsigned short* afsrc = more ? afp : (afp - 4096);
        s16x8 afn[8];
#pragma unroll
        for (int ct = 0; ct < 8; ++ct)
            afn[ct] = *(const s16x8*)(afsrc + ct * 512);
        afp += 4096;

        // 2) issue kf prefetch for NEXT step
        const unsigned short* kfsrc = more ? kfp : (kfp - 2048);
        s16x8 kfn[2][2];
#pragma unroll
        for (int h = 0; h < 2; ++h)
#pragma unroll
            for (int ch = 0; ch < 2; ++ch)
                kfn[h][ch] = *(const s16x8*)(kfsrc + (h * 2 + ch) * 512);
        kfp += 2048;

        // 3) QK with current (prefetched) kf — no wait
        fx4 s[2][2];
#pragma unroll
        for (int qc = 0; qc < 2; ++qc)
#pragma unroll
            for (int h = 0; h < 2; ++h) {
                fx4 a = (fx4){0.f, 0.f, 0.f, 0.f};
                a = __builtin_amdgcn_mfma_f32_16x16x32_bf16(kfc[h][0], qf[qc][0], a, 0, 0, 0);
                a = __builtin_amdgcn_mfma_f32_16x16x32_bf16(kfc[h][1], qf[qc][1], a, 0, 0, 0);
                s[qc][h] = a;
            }

        // 4) P = exp2(s) raw — no max, no rescale, branchless
#pragma unroll
        for (int qc = 0; qc < 2; ++qc) {
            float p0 = fexp2(s[qc][0][0]);
            float p1 = fexp2(s[qc][0][1]);
            float p2 = fexp2(s[qc][0][2]);
            float p3 = fexp2(s[qc][0][3]);
            float p4 = fexp2(s[qc][1][0]);
            float p5 = fexp2(s[qc][1][1]);
            float p6 = fexp2(s[qc][1][2]);
            float p7 = fexp2(s[qc][1][3]);
            pf[qc].w[0] = cvt_pk_bf16(p0, p1);
            pf[qc].w[1] = cvt_pk_bf16(p2, p3);
            pf[qc].w[2] = cvt_pk_bf16(p4, p5);
            pf[qc].w[3] = cvt_pk_bf16(p6, p7);
            // l via ones-row MFMA
            lacc[qc] = __builtin_amdgcn_mfma_f32_16x16x32_bf16(ones, pf[qc].v, lacc[qc], 0, 0, 0);
        }

        // 5) PV with afc (prefetched LAST step — fully arrived)
#pragma unroll
        for (int ct = 0; ct < 8; ++ct) {
            oacc[0][ct] = __builtin_amdgcn_mfma_f32_16x16x32_bf16(afc[ct], pf[0].v, oacc[0][ct], 0, 0, 0);
            oacc[1][ct] = __builtin_amdgcn_mfma_f32_16x16x32_bf16(afc[ct], pf[1].v, oacc[1][ct], 0, 0, 0);
        }

        // 6) rotate prefetch buffers
#pragma unroll
        for (int h = 0; h < 2; ++h)
#pragma unroll
            for (int ch = 0; ch < 2; ++ch)
                kfc[h][ch] = kfn[h][ch];
#pragma unroll
        for (int ct = 0; ct < 8; ++ct)
            afc[ct] = afn[ct];
    }

    // ---- cross-wave combine: denominators just sum (shared scale) ----
    __shared__ float OA[32][CD + 4];
    __shared__ float LL[KSPLIT][32];
    __shared__ float LG[32];

    if (g == 0) {
#pragma unroll
        for (int qc = 0; qc < 2; ++qc)
            LL[wv][qc * 16 + l15] = lacc[qc][0];
    }
    __syncthreads();
    if (threadIdx.x < 32) {
        int q = threadIdx.x;
        float ls = 0.f;
#pragma unroll
        for (int w = 0; w < KSPLIT; ++w) ls += LL[w][q];
        LG[q] = ls;
    }
    for (int w = 0; w < KSPLIT; ++w) {
        if (wv == w) {
#pragma unroll
            for (int qc = 0; qc < 2; ++qc)
#pragma unroll
                for (int ct = 0; ct < 8; ++ct)
#pragma unroll
                    for (int r = 0; r < 4; ++r) {
                        int q = qc * 16 + l15;
                        int c = ct * 16 + g * 4 + r;
                        float v = oacc[qc][ct][r];
                        if (w == 0) OA[q][c] = v; else OA[q][c] += v;
                    }
        }
        __syncthreads();
    }
    {
        const int c = threadIdx.x >> 1;              // [0,128)
        const int qh = (threadIdx.x & 1) * 16;
        float* __restrict__ dst = out + ((size_t)n * CD + c) * HWp + qb + qh;
#pragma unroll
        for (int j = 0; j < 16; ++j) dst[j] = OA[qh + j][c] / LG[qh + j];
    }
}

extern "C" void kernel_launch(void* const* d_in, const int* in_sizes, int n_in,
                              void* d_out, int out_size, void* d_ws, size_t ws_size,
                              hipStream_t stream) {
    const float* x  = (const float*)d_in[0];
    const float* w1 = (const float*)d_in[1];
    const float* b1 = (const float*)d_in[2];
    const float* a1 = (const float*)d_in[3];
    const float* w2 = (const float*)d_in[4];
    const float* b2 = (const float*)d_in[5];
    const float* a2 = (const float*)d_in[6];
    const float* wa = (const float*)d_in[7];
    const float* ba = (const float*)d_in[8];
    const float* aa = (const float*)d_in[9];
    float* out = (float*)d_out;

    char* ws = (char*)d_ws;
    unsigned short* e1  = (unsigned short*)ws;                 // [N][HW][64] bf16 (log2e-scaled)
    unsigned short* e2f = (unsigned short*)(ws + 2359296);     // fragment layout
    unsigned short* avf = (unsigned short*)(ws + 4718592);     // fragment layout
    // total ws usage: 9,437,184 B (proven safe)

    dim3 pg(HWp / 64, NB, 8);
    proj_kernel<<<pg, 256, 0, stream>>>(x, w1, b1, a1, w2, b2, a2, wa, ba, aa, e1, e2f, avf);
    attn_kernel<<<dim3(576), 256, 0, stream>>>(e1, e2f, avf, out);
}

// Round 18
// 182.478 us; speedup vs baseline: 1.1070x; 1.1070x over previous
//
#include <hip/hip_runtime.h>

#define HWp 9216
#define CD 128
#define RC 64
#define NB 2
#define KSPLIT 4
#define NSTEPS 72           // key-blocks of 32 per wave
#define LOG2E 1.4426950408889634f

// fragment-layout strides (in shorts)
#define E2F_NSTR 589824     // (HWp/32) kb * 4 frags * 64 lanes * 8
#define AVF_NSTR 1179648    // (HWp/32) kb * 8 frags * 64 lanes * 8

typedef short s16x8 __attribute__((ext_vector_type(8)));
typedef unsigned short u16x8 __attribute__((ext_vector_type(8)));
typedef float fx4 __attribute__((ext_vector_type(4)));

__device__ __forceinline__ unsigned short f2bf(float f) {
    union { float f; unsigned int u; } cv; cv.f = f;
    unsigned int u = cv.u;
    u += 0x7FFFu + ((u >> 16) & 1u);
    return (unsigned short)(u >> 16);
}

__device__ __forceinline__ float fexp2(float x) {
    float r; asm("v_exp_f32 %0, %1" : "=v"(r) : "v"(x)); return r;
}

__device__ __forceinline__ unsigned int cvt_pk_bf16(float lo, float hi) {
    unsigned int r; asm("v_cvt_pk_bf16_f32 %0, %1, %2" : "=v"(r) : "v"(lo), "v"(hi)); return r;
}

__device__ __forceinline__ const float* uniform_ptr(const float* p) {
    unsigned long long v = (unsigned long long)(uintptr_t)p;
    unsigned int lo = __builtin_amdgcn_readfirstlane((unsigned int)v);
    unsigned int hi = __builtin_amdgcn_readfirstlane((unsigned int)(v >> 32));
    return (const float*)(uintptr_t)(((unsigned long long)hi << 32) | lo);
}

// Projections. R12-VERBATIM (passed R12/R14/R16, ~72-75us). Grid (144, NB, 8); 256 thr.
__global__ __launch_bounds__(256) void proj_kernel(
    const float* __restrict__ x,
    const float* __restrict__ w1, const float* __restrict__ b1, const float* __restrict__ a1,
    const float* __restrict__ w2, const float* __restrict__ b2, const float* __restrict__ a2,
    const float* __restrict__ wa, const float* __restrict__ ba, const float* __restrict__ aa,
    unsigned short* __restrict__ e1, unsigned short* __restrict__ e2f,
    unsigned short* __restrict__ avf)
{
    const int n = blockIdx.y;
    const int p0 = blockIdx.x * 64;
    const int wv = threadIdx.x >> 6;
    const int lane = threadIdx.x & 63;
    const int p = p0 + lane;
    const int row0 = blockIdx.z * 32 + wv * 8;   // 0..255 in [e1(64) | e2(64) | av(128)]
    const float* __restrict__ xb = x + (size_t)n * CD * HWp;

    const float* W; const float* B; const float* A; int r0; int mode; float oscale = 1.0f;
    if (row0 < 64)       { W = w1; B = b1; A = a1; r0 = row0;       mode = 0; oscale = LOG2E; }
    else if (row0 < 128) { W = w2; B = b2; A = a2; r0 = row0 - 64;  mode = 1; }
    else                 { W = wa; B = ba; A = aa; r0 = row0 - 128; mode = 2; }
    W = uniform_ptr(W); B = uniform_ptr(B);
    const float slope = A[0];

    float acc[8];
#pragma unroll
    for (int j = 0; j < 8; ++j) acc[j] = B[r0 + j];
    for (int cc = 0; cc < 4; ++cc) {
        float xr[32];
#pragma unroll
        for (int i = 0; i < 32; ++i) xr[i] = xb[(size_t)(cc * 32 + i) * HWp + p];
#pragma unroll
        for (int j = 0; j < 8; ++j) {
            const float* Wr = W + (size_t)(r0 + j) * CD + cc * 32;
            float a = acc[j];
#pragma unroll
            for (int i = 0; i < 32; ++i) a = __builtin_fmaf(Wr[i], xr[i], a);
            acc[j] = a;
        }
    }
#pragma unroll
    for (int j = 0; j < 8; ++j) {
        float v = acc[j];
        acc[j] = (v >= 0.f ? v : slope * v) * oscale;
    }
    if (mode == 0) {
        u16x8 s0;
#pragma unroll
        for (int j = 0; j < 8; ++j) s0[j] = f2bf(acc[j]);
        unsigned short* dst = e1 + ((size_t)n * HWp + p) * RC + r0;
        *(u16x8*)(dst) = s0;
    } else if (mode == 1) {
        u16x8 s0;
#pragma unroll
        for (int j = 0; j < 8; ++j) s0[j] = f2bf(acc[j]);
        const int kb = p >> 5, kk = p & 31;
        const int l15w = ((kk >> 3) << 2) | (kk & 3);
        const int hw = (kk >> 2) & 1;
        const int ch = r0 >> 5;
        const int gA = (r0 >> 3) & 3;
        unsigned short* dst = e2f + (size_t)n * E2F_NSTR
                            + ((size_t)((kb * 4 + hw * 2 + ch) * 64 + gA * 16 + l15w)) * 8;
        *(u16x8*)(dst) = s0;
    } else {
        const int kb = p >> 5, gw = (p >> 3) & 3, jj = p & 7;
        const int ct = r0 >> 4;
        const int lbase = r0 & 15;
        unsigned short* base = avf + (size_t)n * AVF_NSTR
                             + ((size_t)((kb * 8 + ct) * 64 + gw * 16)) * 8 + jj;
#pragma unroll
        for (int j = 0; j < 8; ++j)
            base[(lbase + j) * 8] = f2bf(acc[j]);
    }
}

// Flash attention. R13/R16-VERBATIM (passed twice, 107.4us): branchless no-max
// inner loop, running pointers, af at step top, kf rotation; 576 blocks x 256 thr.
__global__ __launch_bounds__(256, 1) void attn_kernel(
    const unsigned short* __restrict__ e1,
    const unsigned short* __restrict__ e2f,
    const unsigned short* __restrict__ avf,
    float* __restrict__ out)
{
    const int wv = threadIdx.x >> 6;
    const int lane = threadIdx.x & 63;
    const int g = lane >> 4;
    const int l15 = lane & 15;

    // XCD swizzle (R2-verbatim): batch 0 -> XCDs 0-3, batch 1 -> XCDs 4-7
    const int bid = blockIdx.x;
    const int xcd = bid & 7;
    const int n = xcd >> 2;
    const int qslot = (xcd & 3) * 72 + (bid >> 3);   // [0,288)
    const int qb = qslot * 32;

    const unsigned short* __restrict__ E1 = e1 + (size_t)n * HWp * RC;
    const unsigned short* __restrict__ E2F = e2f + (size_t)n * E2F_NSTR;
    const unsigned short* __restrict__ AVF = avf + (size_t)n * AVF_NSTR;

    // Q fragments (B operand): col = query = l15, k = channel = ch*32 + g*8 + j
    s16x8 qf[2][2];
#pragma unroll
    for (int qc = 0; qc < 2; ++qc)
#pragma unroll
        for (int ch = 0; ch < 2; ++ch)
            qf[qc][ch] = *(const s16x8*)(E1 + ((size_t)(qb + qc * 16 + l15)) * RC + ch * 32 + g * 8);

    s16x8 ones;
#pragma unroll
    for (int j = 0; j < 8; ++j) ones[j] = (short)0x3F80;   // bf16 1.0

    fx4 oacc[2][8];
    fx4 lacc[2];
#pragma unroll
    for (int qc = 0; qc < 2; ++qc) {
        lacc[qc] = (fx4){0.f, 0.f, 0.f, 0.f};
#pragma unroll
        for (int ct = 0; ct < 8; ++ct) oacc[qc][ct] = (fx4){0.f, 0.f, 0.f, 0.f};
    }

    const int kb0 = wv * NSTEPS;   // first key-block of this wave

    // running pointers (shorts): kf frag f at kfp + f*512; af frag ct at afp + ct*512
    const unsigned short* kfp = E2F + (size_t)kb0 * 2048 + (size_t)lane * 8;
    const unsigned short* afp = AVF + (size_t)kb0 * 4096 + (size_t)lane * 8;

    // prologue: prefetch kf for kb0
    s16x8 kfc[2][2];
#pragma unroll
    for (int h = 0; h < 2; ++h)
#pragma unroll
        for (int ch = 0; ch < 2; ++ch)
            kfc[h][ch] = *(const s16x8*)(kfp + (h * 2 + ch) * 512);
    kfp += 2048;

    union { s16x8 v; unsigned int w[4]; } pf[2];

    for (int kt = 0; kt < NSTEPS; ++kt) {
        // 1) issue ALL af loads for CURRENT step (fly during QK+softmax)
        s16x8 af[8];
#pragma unroll
        for (int ct = 0; ct < 8; ++ct)
            af[ct] = *(const s16x8*)(afp + ct * 512);
        afp += 4096;

        // 2) issue kf prefetch for NEXT step
        const unsigned short* kfsrc = (kt + 1 < NSTEPS) ? kfp : (kfp - 2048);
        s16x8 kfn[2][2];
#pragma unroll
        for (int h = 0; h < 2; ++h)
#pragma unroll
            for (int ch = 0; ch < 2; ++ch)
                kfn[h][ch] = *(const s16x8*)(kfsrc + (h * 2 + ch) * 512);
        kfp += 2048;

        // 3) QK with current (prefetched) kf — no wait
        fx4 s[2][2];
#pragma unroll
        for (int qc = 0; qc < 2; ++qc)
#pragma unroll
            for (int h = 0; h < 2; ++h) {
                fx4 a = (fx4){0.f, 0.f, 0.f, 0.f};
                a = __builtin_amdgcn_mfma_f32_16x16x32_bf16(kfc[h][0], qf[qc][0], a, 0, 0, 0);
                a = __builtin_amdgcn_mfma_f32_16x16x32_bf16(kfc[h][1], qf[qc][1], a, 0, 0, 0);
                s[qc][h] = a;
            }

        // 4) P = exp2(s) raw — no max, no rescale, branchless
#pragma unroll
        for (int qc = 0; qc < 2; ++qc) {
            float p0 = fexp2(s[qc][0][0]);
            float p1 = fexp2(s[qc][0][1]);
            float p2 = fexp2(s[qc][0][2]);
            float p3 = fexp2(s[qc][0][3]);
            float p4 = fexp2(s[qc][1][0]);
            float p5 = fexp2(s[qc][1][1]);
            float p6 = fexp2(s[qc][1][2]);
            float p7 = fexp2(s[qc][1][3]);
            pf[qc].w[0] = cvt_pk_bf16(p0, p1);
            pf[qc].w[1] = cvt_pk_bf16(p2, p3);
            pf[qc].w[2] = cvt_pk_bf16(p4, p5);
            pf[qc].w[3] = cvt_pk_bf16(p6, p7);
            // l via ones-row MFMA
            lacc[qc] = __builtin_amdgcn_mfma_f32_16x16x32_bf16(ones, pf[qc].v, lacc[qc], 0, 0, 0);
        }

        // 5) PV with af (arrived during QK+softmax)
#pragma unroll
        for (int ct = 0; ct < 8; ++ct) {
            oacc[0][ct] = __builtin_amdgcn_mfma_f32_16x16x32_bf16(af[ct], pf[0].v, oacc[0][ct], 0, 0, 0);
            oacc[1][ct] = __builtin_amdgcn_mfma_f32_16x16x32_bf16(af[ct], pf[1].v, oacc[1][ct], 0, 0, 0);
        }

        // 6) rotate kf prefetch
#pragma unroll
        for (int h = 0; h < 2; ++h)
#pragma unroll
            for (int ch = 0; ch < 2; ++ch)
                kfc[h][ch] = kfn[h][ch];
    }

    // ---- cross-wave combine: denominators just sum (shared scale) ----
    __shared__ float OA[32][CD + 4];
    __shared__ float LL[KSPLIT][32];
    __shared__ float LG[32];

    if (g == 0) {
#pragma unroll
        for (int qc = 0; qc < 2; ++qc)
            LL[wv][qc * 16 + l15] = lacc[qc][0];
    }
    __syncthreads();
    if (threadIdx.x < 32) {
        int q = threadIdx.x;
        float ls = 0.f;
#pragma unroll
        for (int w = 0; w < KSPLIT; ++w) ls += LL[w][q];
        LG[q] = ls;
    }
    for (int w = 0; w < KSPLIT; ++w) {
        if (wv == w) {
#pragma unroll
            for (int qc = 0; qc < 2; ++qc)
#pragma unroll
                for (int ct = 0; ct < 8; ++ct)
#pragma unroll
                    for (int r = 0; r < 4; ++r) {
                        int q = qc * 16 + l15;
                        int c = ct * 16 + g * 4 + r;
                        float v = oacc[qc][ct][r];
                        if (w == 0) OA[q][c] = v; else OA[q][c] += v;
                    }
        }
        __syncthreads();
    }
    {
        const int c = threadIdx.x >> 1;              // [0,128)
        const int qh = (threadIdx.x & 1) * 16;
        float* __restrict__ dst = out + ((size_t)n * CD + c) * HWp + qb + qh;
#pragma unroll
        for (int j = 0; j < 16; ++j) dst[j] = OA[qh + j][c] / LG[qh + j];
    }
}

extern "C" void kernel_launch(void* const* d_in, const int* in_sizes, int n_in,
                              void* d_out, int out_size, void* d_ws, size_t ws_size,
                              hipStream_t stream) {
    const float* x  = (const float*)d_in[0];
    const float* w1 = (const float*)d_in[1];
    const float* b1 = (const float*)d_in[2];
    const float* a1 = (const float*)d_in[3];
    const float* w2 = (const float*)d_in[4];
    const float* b2 = (const float*)d_in[5];
    const float* a2 = (const float*)d_in[6];
    const float* wa = (const float*)d_in[7];
    const float* ba = (const float*)d_in[8];
    const float* aa = (const float*)d_in[9];
    float* out = (float*)d_out;

    char* ws = (char*)d_ws;
    unsigned short* e1  = (unsigned short*)ws;                 // [N][HW][64] bf16 (log2e-scaled)
    unsigned short* e2f = (unsigned short*)(ws + 2359296);     // fragment layout
    unsigned short* avf = (unsigned short*)(ws + 4718592);     // fragment layout
    // total ws usage: 9,437,184 B (proven safe)

    dim3 pg(HWp / 64, NB, 8);
    proj_kernel<<<pg, 256, 0, stream>>>(x, w1, b1, a1, w2, b2, a2, wa, ba, aa, e1, e2f, avf);
    attn_kernel<<<dim3(576), 256, 0, stream>>>(e1, e2f, avf, out);
}